// Round 16
// baseline (35.684 us; speedup 1.0000x reference)
//
#include <hip/hip_runtime.h>
#include <hip/hip_fp16.h>

// Problem constants (from reference setup_inputs)
constexpr int Bn = 256;
constexpr int Nn = 16384;
constexpr int Hh = 96;
constexpr int Ww = 96;

constexpr int THREADS = 1024;
constexpr int CHUNKS  = 2;                 // 512 blocks -> 2 per CU -> 32 waves/CU

// Dup-pair fp16 LDS entries (4B): entry c = (pad[c], pad[c+1]).
//   Edge: pad rows 0..99 (2-zero pad each side), 100x100 = 10000 entries
//   Mask: pad rows 1..98 stored as s-rows 0..97,   98x100 =  9800 entries
// Total 19800 x 4B = 79.2 KB -> 2 blocks/CU.
// Per corner: edge 4x4 = 4 ds_read2_b32, mask 2x2 = 1 ds_read2_b32.
constexpr int MOFF = 10000;
constexpr int TOTENT = 19800;

static __device__ inline float2 up2(__half2 h) { return __half22float2(h); }

// ---- per-corner macros; all locals SCOPED (fresh per iteration -> SSA) ----
#define ADDR(sfx, CX, CY)                                                   \
    float ix##sfx = fmaf(CX, 96.f, -0.5f);                                  \
    float iy##sfx = fmaf(CY, 96.f, -0.5f);                                  \
    float fx##sfx = floorf(ix##sfx), fy##sfx = floorf(iy##sfx);             \
    float wx##sfx = ix##sfx - fx##sfx, wy##sfx = iy##sfx - fy##sfx;         \
    int v##sfx  = (int)fy##sfx * 100 + (int)fx##sfx;                        \
    int cb##sfx = v##sfx + 101;                                             \
    int c3##sfx = v##sfx + 401;                                             \
    int mb##sfx = v##sfx + MOFF + 102;

#define ISSUE(sfx)                                                          \
    __half2 a0##sfx = sB[cb##sfx],       d0##sfx = sB[cb##sfx + 2];         \
    __half2 a1##sfx = sB[cb##sfx + 100], d1##sfx = sB[cb##sfx + 102];       \
    __half2 a2##sfx = sB[cb##sfx + 200], d2##sfx = sB[cb##sfx + 202];       \
    __half2 a3##sfx = sB[c3##sfx],       d3##sfx = sB[c3##sfx + 2];         \
    __half2 ma##sfx = sB[mb##sfx],       mc##sfx = sB[mb##sfx + 100];

#define COMPUTE(sfx)                                                        \
    {                                                                       \
        float2 A0 = up2(a0##sfx), D0 = up2(d0##sfx);                        \
        float2 A1 = up2(a1##sfx), D1 = up2(d1##sfx);                        \
        float2 A2 = up2(a2##sfx), D2 = up2(d2##sfx);                        \
        float2 A3 = up2(a3##sfx), D3 = up2(d3##sfx);                        \
        float wx = wx##sfx, wy = wy##sfx;                                   \
        float h00 = fmaf(wx, A0.y - A0.x, A0.x);                            \
        float h01 = fmaf(wx, D0.x - A0.y, A0.y);                            \
        float h02 = fmaf(wx, D0.y - D0.x, D0.x);                            \
        float h10 = fmaf(wx, A1.y - A1.x, A1.x);                            \
        float h11 = fmaf(wx, D1.x - A1.y, A1.y);                            \
        float h12 = fmaf(wx, D1.y - D1.x, D1.x);                            \
        float h20 = fmaf(wx, A2.y - A2.x, A2.x);                            \
        float h21 = fmaf(wx, D2.x - A2.y, A2.y);                            \
        float h22 = fmaf(wx, D2.y - D2.x, D2.x);                            \
        float h30 = fmaf(wx, A3.y - A3.x, A3.x);                            \
        float h31 = fmaf(wx, D3.x - A3.y, A3.y);                            \
        float h32 = fmaf(wx, D3.y - D3.x, D3.x);                            \
        float v00 = fmaf(wy, h10 - h00, h00);                               \
        float v01 = fmaf(wy, h11 - h01, h01);                               \
        float v02 = fmaf(wy, h12 - h02, h02);                               \
        float v10 = fmaf(wy, h20 - h10, h10);                               \
        float v11 = fmaf(wy, h21 - h11, h11);                               \
        float v12 = fmaf(wy, h22 - h12, h12);                               \
        float v20 = fmaf(wy, h30 - h20, h20);                               \
        float v21 = fmaf(wy, h31 - h21, h21);                               \
        float v22 = fmaf(wy, h32 - h22, h22);                               \
        float best = fmaxf(fmaxf(fmaxf(v00, v01), fmaxf(v02, v10)),         \
                           fmaxf(fmaxf(v11, v12),                           \
                                 fmaxf(fmaxf(v20, v21), v22)));             \
        eAcc += best;                                                       \
        float2 qa = up2(ma##sfx), qc = up2(mc##sfx);                        \
        float t = fmaf(wx, qa.y - qa.x, qa.x);                              \
        float u = fmaf(wx, qc.y - qc.x, qc.x);                              \
        float m = fmaf(wy, u - t, t);                                       \
        float d = m - 0.5f;                                                 \
        mAcc = fmaf(d, d, mAcc);                                            \
    }

__global__ __launch_bounds__(THREADS, 8)
void geo_kernel(const float* __restrict__ corners,
                const float* __restrict__ edge,
                const float* __restrict__ mask,
                float2* __restrict__ partial,      // [512] block partials
                unsigned* __restrict__ cnt,        // zeroed per launch
                float* __restrict__ out)
{
    __shared__ __half2 sB[TOTENT];
    __shared__ float  redE[THREADS / 64];
    __shared__ float  redM[THREADS / 64];
    __shared__ double rDE[8];
    __shared__ double rDM[8];
    __shared__ unsigned isLast;

    const int b     = blockIdx.x >> 1;     // CHUNKS == 2
    const int chunk = blockIdx.x & 1;
    const int tid   = threadIdx.x;

    // --- zero border entries (disjoint from interior fill) ---
    {
        const __half2 z2 = __halves2half2(__ushort_as_half(0), __ushort_as_half(0));
        for (int i = tid; i < 1176; i += THREADS) {
            int idx;
            if (i < 200)        idx = i;                          // edge pad rows 0,1
            else if (i < 400)   idx = 9600 + i;                   // edge pad rows 98,99
            else if (i < 500)   idx = MOFF + (i - 400);           // mask s-row 0
            else if (i < 600)   idx = MOFF + 9200 + i;            // mask s-row 97
            else if (i < 888) { int k = i - 600; int r = k / 3; int c3 = k - 3 * r;
                                int c = (c3 == 0) ? 0 : (97 + c3);
                                idx = (r + 2) * 100 + c; }        // edge rows 2..97
            else              { int k = i - 888; int r = k / 3; int c3 = k - 3 * r;
                                int c = (c3 == 0) ? 0 : (97 + c3);
                                idx = MOFF + (r + 1) * 100 + c; } // mask s-rows 1..96
            sB[idx] = z2;
        }
    }

    // --- fill interiors with dup-pair fp16 (disjoint from borders) ---
    {
        const float* ebase = edge + (size_t)b * Hh * Ww;
        const float* mbase = mask + (size_t)b * Hh * Ww;
        for (int i = tid; i < 96 * 48; i += THREADS) {
            int r = i / 48;
            int j = i - 48 * r;
            const float* erow = ebase + r * Ww;
            const float* mrow = mbase + r * Ww;
            float2 ae = *(const float2*)(erow + 2 * j);
            float2 am = *(const float2*)(mrow + 2 * j);
            float ne = (2 * j + 2 < Ww) ? erow[2 * j + 2] : 0.f;
            float nm = (2 * j + 2 < Ww) ? mrow[2 * j + 2] : 0.f;
            int eb2 = (r + 2) * 100 + 2 * j + 2;
            sB[eb2]     = __float22half2_rn(make_float2(ae.x, ae.y));
            sB[eb2 + 1] = __float22half2_rn(make_float2(ae.y, ne));
            int mb2 = MOFF + (r + 1) * 100 + 2 * j + 2;
            sB[mb2]     = __float22half2_rn(make_float2(am.x, am.y));
            sB[mb2 + 1] = __float22half2_rn(make_float2(am.y, nm));
            if (j == 0) {
                sB[(r + 2) * 100 + 1]        = __float22half2_rn(make_float2(0.f, ae.x));
                sB[MOFF + (r + 1) * 100 + 1] = __float22half2_rn(make_float2(0.f, am.x));
            }
        }
    }
    __syncthreads();

    // --- corner loop: 4 float4 (8 corners), pairwise software-pipelined (R12) ---
    const float4* c4 =
        (const float4*)(corners + (size_t)b * Nn * 2 + (size_t)chunk * (Nn / CHUNKS) * 2);
    float eAcc = 0.f, mAcc = 0.f;

    float4 nxt = c4[tid];
#pragma unroll
    for (int k = 0; k < 4; ++k) {
        float4 cur = nxt;
        if (k < 3) nxt = c4[(k + 1) * THREADS + tid];   // prefetch next pair

        ADDR(A, cur.x, cur.y)
        ISSUE(A)                      // 5 ds_read2 for corner A in flight
        ADDR(B, cur.z, cur.w)
        ISSUE(B)                      // 5 more for corner B in flight
        COMPUTE(A)                    // waits only on A's reads
        COMPUTE(B)
    }

    // --- per-block reduce: wave shuffle, cross-wave via LDS ---
#pragma unroll
    for (int off = 32; off > 0; off >>= 1) {
        eAcc += __shfl_xor(eAcc, off);
        mAcc += __shfl_xor(mAcc, off);
    }
    const int wv = tid >> 6;
    const int ln = tid & 63;
    if (ln == 0) { redE[wv] = eAcc; redM[wv] = mAcc; }
    __syncthreads();

    if (tid == 0) {
        float e = 0.f, m = 0.f;
#pragma unroll
        for (int w = 0; w < THREADS / 64; ++w) { e += redE[w]; m += redM[w]; }
        partial[blockIdx.x] = make_float2(e, m);
        __threadfence();                    // publish partial device-wide
        unsigned old = atomicAdd(cnt, 1u);
        isLast = (old == (unsigned)(gridDim.x - 1)) ? 1u : 0u;
    }
    __syncthreads();

    // --- last block finalizes: coherent atomic reads of all 512 partials ---
    if (isLast) {
        double e = 0.0, m = 0.0;
        if (tid < 512) {
            float pe = atomicAdd(&((float*)partial)[2 * tid + 0], 0.f);
            float pm = atomicAdd(&((float*)partial)[2 * tid + 1], 0.f);
            e = (double)pe;
            m = (double)pm;
        }
#pragma unroll
        for (int off = 32; off > 0; off >>= 1) {
            e += __shfl_xor(e, off);
            m += __shfl_xor(m, off);
        }
        if (tid < 512 && ln == 0) { rDE[wv] = e; rDM[wv] = m; }
        __syncthreads();
        if (tid == 0) {
            double se = 0.0, sm = 0.0;
#pragma unroll
            for (int w = 0; w < 8; ++w) { se += rDE[w]; sm += rDM[w]; }
            const double inv = 1.0 / (double)((long long)Bn * (long long)Nn);
            double edge_loss = 1.0 - se * inv;
            double mask_loss = sm * inv;
            out[0] = (float)(edge_loss + 2.0 * mask_loss);
        }
    }
}

extern "C" void kernel_launch(void* const* d_in, const int* in_sizes, int n_in,
                              void* d_out, int out_size, void* d_ws, size_t ws_size,
                              hipStream_t stream)
{
    const float* corners = (const float*)d_in[0];
    const float* edge    = (const float*)d_in[1];
    const float* mask    = (const float*)d_in[2];
    float* out      = (float*)d_out;
    float2* partial = (float2*)d_ws;                       // 512 float2
    unsigned* cnt   = (unsigned*)((char*)d_ws + 512 * sizeof(float2));

    hipMemsetAsync(cnt, 0, sizeof(unsigned), stream);
    geo_kernel<<<Bn * CHUNKS, THREADS, 0, stream>>>(corners, edge, mask,
                                                    partial, cnt, out);
}

// Round 17
// 25.385 us; speedup vs baseline: 1.4057x; 1.4057x over previous
//
#include <hip/hip_runtime.h>
#include <hip/hip_fp16.h>

// Problem constants (from reference setup_inputs)
constexpr int Bn = 256;
constexpr int Nn = 16384;
constexpr int Hh = 96;
constexpr int Ww = 96;

constexpr int THREADS = 1024;
constexpr int CHUNKS  = 2;                 // 512 blocks -> 2 per CU -> 32 waves/CU

// Dup-pair fp16 LDS entries (4B): entry c = (pad[c], pad[c+1]).
//   Edge: pad rows 0..99 (2-zero pad each side), 100x100 = 10000 entries
//   Mask: pad rows 1..98 stored as s-rows 0..97,   98x100 =  9800 entries
// Total 19800 x 4B = 79.2 KB -> 2 blocks/CU.
// Per corner: edge 4x4 = 4 ds_read2_b32, mask 2x2 = 1 ds_read2_b32.
constexpr int MOFF = 10000;
constexpr int TOTENT = 19800;

static __device__ inline float2 up2(__half2 h) { return __half22float2(h); }

// ---- per-corner macros; all locals SCOPED (fresh per iteration -> SSA) ----
#define ADDR(sfx, CX, CY)                                                   \
    float ix##sfx = fmaf(CX, 96.f, -0.5f);                                  \
    float iy##sfx = fmaf(CY, 96.f, -0.5f);                                  \
    float fx##sfx = floorf(ix##sfx), fy##sfx = floorf(iy##sfx);             \
    float wx##sfx = ix##sfx - fx##sfx, wy##sfx = iy##sfx - fy##sfx;         \
    int v##sfx  = (int)fy##sfx * 100 + (int)fx##sfx;                        \
    int cb##sfx = v##sfx + 101;                                             \
    int c3##sfx = v##sfx + 401;                                             \
    int mb##sfx = v##sfx + MOFF + 102;

#define ISSUE(sfx)                                                          \
    __half2 a0##sfx = sB[cb##sfx],       d0##sfx = sB[cb##sfx + 2];         \
    __half2 a1##sfx = sB[cb##sfx + 100], d1##sfx = sB[cb##sfx + 102];       \
    __half2 a2##sfx = sB[cb##sfx + 200], d2##sfx = sB[cb##sfx + 202];       \
    __half2 a3##sfx = sB[c3##sfx],       d3##sfx = sB[c3##sfx + 2];         \
    __half2 ma##sfx = sB[mb##sfx],       mc##sfx = sB[mb##sfx + 100];

#define COMPUTE(sfx)                                                        \
    {                                                                       \
        float2 A0 = up2(a0##sfx), D0 = up2(d0##sfx);                        \
        float2 A1 = up2(a1##sfx), D1 = up2(d1##sfx);                        \
        float2 A2 = up2(a2##sfx), D2 = up2(d2##sfx);                        \
        float2 A3 = up2(a3##sfx), D3 = up2(d3##sfx);                        \
        float wx = wx##sfx, wy = wy##sfx;                                   \
        float h00 = fmaf(wx, A0.y - A0.x, A0.x);                            \
        float h01 = fmaf(wx, D0.x - A0.y, A0.y);                            \
        float h02 = fmaf(wx, D0.y - D0.x, D0.x);                            \
        float h10 = fmaf(wx, A1.y - A1.x, A1.x);                            \
        float h11 = fmaf(wx, D1.x - A1.y, A1.y);                            \
        float h12 = fmaf(wx, D1.y - D1.x, D1.x);                            \
        float h20 = fmaf(wx, A2.y - A2.x, A2.x);                            \
        float h21 = fmaf(wx, D2.x - A2.y, A2.y);                            \
        float h22 = fmaf(wx, D2.y - D2.x, D2.x);                            \
        float h30 = fmaf(wx, A3.y - A3.x, A3.x);                            \
        float h31 = fmaf(wx, D3.x - A3.y, A3.y);                            \
        float h32 = fmaf(wx, D3.y - D3.x, D3.x);                            \
        float v00 = fmaf(wy, h10 - h00, h00);                               \
        float v01 = fmaf(wy, h11 - h01, h01);                               \
        float v02 = fmaf(wy, h12 - h02, h02);                               \
        float v10 = fmaf(wy, h20 - h10, h10);                               \
        float v11 = fmaf(wy, h21 - h11, h11);                               \
        float v12 = fmaf(wy, h22 - h12, h12);                               \
        float v20 = fmaf(wy, h30 - h20, h20);                               \
        float v21 = fmaf(wy, h31 - h21, h21);                               \
        float v22 = fmaf(wy, h32 - h22, h22);                               \
        float best = fmaxf(fmaxf(fmaxf(v00, v01), fmaxf(v02, v10)),         \
                           fmaxf(fmaxf(v11, v12),                           \
                                 fmaxf(fmaxf(v20, v21), v22)));             \
        eAcc += best;                                                       \
        float2 qa = up2(ma##sfx), qc = up2(mc##sfx);                        \
        float t = fmaf(wx, qa.y - qa.x, qa.x);                              \
        float u = fmaf(wx, qc.y - qc.x, qc.x);                              \
        float m = fmaf(wy, u - t, t);                                       \
        float d = m - 0.5f;                                                 \
        mAcc = fmaf(d, d, mAcc);                                            \
    }

__global__ __launch_bounds__(THREADS, 8)
void geo_kernel(const float* __restrict__ corners,
                const float* __restrict__ edge,
                const float* __restrict__ mask,
                float2* __restrict__ partial)
{
    __shared__ __half2 sB[TOTENT];
    __shared__ float redE[THREADS / 64];
    __shared__ float redM[THREADS / 64];

    const int b     = blockIdx.x >> 1;     // CHUNKS == 2
    const int chunk = blockIdx.x & 1;
    const int tid   = threadIdx.x;

    // --- zero border entries (disjoint from interior fill) ---
    {
        const __half2 z2 = __halves2half2(__ushort_as_half(0), __ushort_as_half(0));
        for (int i = tid; i < 1176; i += THREADS) {
            int idx;
            if (i < 200)        idx = i;                          // edge pad rows 0,1
            else if (i < 400)   idx = 9600 + i;                   // edge pad rows 98,99
            else if (i < 500)   idx = MOFF + (i - 400);           // mask s-row 0
            else if (i < 600)   idx = MOFF + 9200 + i;            // mask s-row 97
            else if (i < 888) { int k = i - 600; int r = k / 3; int c3 = k - 3 * r;
                                int c = (c3 == 0) ? 0 : (97 + c3);
                                idx = (r + 2) * 100 + c; }        // edge rows 2..97
            else              { int k = i - 888; int r = k / 3; int c3 = k - 3 * r;
                                int c = (c3 == 0) ? 0 : (97 + c3);
                                idx = MOFF + (r + 1) * 100 + c; } // mask s-rows 1..96
            sB[idx] = z2;
        }
    }

    // --- fill interiors with dup-pair fp16 (disjoint from borders) ---
    {
        const float* ebase = edge + (size_t)b * Hh * Ww;
        const float* mbase = mask + (size_t)b * Hh * Ww;
        for (int i = tid; i < 96 * 48; i += THREADS) {
            int r = i / 48;
            int j = i - 48 * r;
            const float* erow = ebase + r * Ww;
            const float* mrow = mbase + r * Ww;
            float2 ae = *(const float2*)(erow + 2 * j);
            float2 am = *(const float2*)(mrow + 2 * j);
            float ne = (2 * j + 2 < Ww) ? erow[2 * j + 2] : 0.f;
            float nm = (2 * j + 2 < Ww) ? mrow[2 * j + 2] : 0.f;
            int eb2 = (r + 2) * 100 + 2 * j + 2;
            sB[eb2]     = __float22half2_rn(make_float2(ae.x, ae.y));
            sB[eb2 + 1] = __float22half2_rn(make_float2(ae.y, ne));
            int mb2 = MOFF + (r + 1) * 100 + 2 * j + 2;
            sB[mb2]     = __float22half2_rn(make_float2(am.x, am.y));
            sB[mb2 + 1] = __float22half2_rn(make_float2(am.y, nm));
            if (j == 0) {
                sB[(r + 2) * 100 + 1]        = __float22half2_rn(make_float2(0.f, ae.x));
                sB[MOFF + (r + 1) * 100 + 1] = __float22half2_rn(make_float2(0.f, am.x));
            }
        }
    }
    __syncthreads();

    // --- corner loop: 4 float4 (8 corners), pairwise software-pipelined ---
    const float4* c4 =
        (const float4*)(corners + (size_t)b * Nn * 2 + (size_t)chunk * (Nn / CHUNKS) * 2);
    float eAcc = 0.f, mAcc = 0.f;

    float4 nxt = c4[tid];
#pragma unroll
    for (int k = 0; k < 4; ++k) {
        float4 cur = nxt;
        if (k < 3) nxt = c4[(k + 1) * THREADS + tid];   // prefetch next pair

        ADDR(A, cur.x, cur.y)
        ISSUE(A)                      // 5 ds_read2 for corner A in flight
        ADDR(B, cur.z, cur.w)
        ISSUE(B)                      // 5 more for corner B in flight
        COMPUTE(A)                    // waits only on A's reads
        COMPUTE(B)
    }

    // --- reduce: wave shuffle, cross-wave via LDS, per-block partial ---
#pragma unroll
    for (int off = 32; off > 0; off >>= 1) {
        eAcc += __shfl_xor(eAcc, off);
        mAcc += __shfl_xor(mAcc, off);
    }
    const int wv = tid >> 6;
    const int ln = tid & 63;
    if (ln == 0) { redE[wv] = eAcc; redM[wv] = mAcc; }
    __syncthreads();

    if (tid == 0) {
        float e = 0.f, m = 0.f;
#pragma unroll
        for (int w = 0; w < THREADS / 64; ++w) { e += redE[w]; m += redM[w]; }
        partial[blockIdx.x] = make_float2(e, m);
    }
}

// Final reduction over the 512 block partials; no atomics anywhere.
__global__ __launch_bounds__(512)
void geo_reduce(const float2* __restrict__ partial, float* __restrict__ out)
{
    __shared__ double rE[8];
    __shared__ double rM[8];
    const int tid = threadIdx.x;
    float2 p = partial[tid];
    double e = (double)p.x, m = (double)p.y;
#pragma unroll
    for (int off = 32; off > 0; off >>= 1) {
        e += __shfl_xor(e, off);
        m += __shfl_xor(m, off);
    }
    if ((tid & 63) == 0) { rE[tid >> 6] = e; rM[tid >> 6] = m; }
    __syncthreads();
    if (tid == 0) {
        double se = 0.0, sm = 0.0;
#pragma unroll
        for (int w = 0; w < 8; ++w) { se += rE[w]; sm += rM[w]; }
        const double inv = 1.0 / (double)((long long)Bn * (long long)Nn);
        double edge_loss = 1.0 - se * inv;
        double mask_loss = sm * inv;
        out[0] = (float)(edge_loss + 2.0 * mask_loss);
    }
}

extern "C" void kernel_launch(void* const* d_in, const int* in_sizes, int n_in,
                              void* d_out, int out_size, void* d_ws, size_t ws_size,
                              hipStream_t stream)
{
    const float* corners = (const float*)d_in[0];
    const float* edge    = (const float*)d_in[1];
    const float* mask    = (const float*)d_in[2];
    float* out      = (float*)d_out;
    float2* partial = (float2*)d_ws;

    geo_kernel<<<Bn * CHUNKS, THREADS, 0, stream>>>(corners, edge, mask, partial);
    geo_reduce<<<1, 512, 0, stream>>>(partial, out);
}